// Round 1
// baseline (238.595 us; speedup 1.0000x reference)
//
#include <hip/hip_runtime.h>

#define DDIM 4096
#define ADIM 21
#define NSEG 8
#define SEG  (DDIM / NSEG)   // 512
#define BROWS 256            // rows per block == threads per block

// Thread-per-row: W[a][d] index is wave-uniform -> one (scalar/broadcast) load
// serves 64 rows. x loads are per-lane 16B but walk the row contiguously so
// every HBM line is fully used. D split into NSEG segments for parallelism;
// partials combined via fp32 atomicAdd (device scope, cross-XCD safe).
__global__ __launch_bounds__(BROWS, 2)
void fem_kernel(const float* __restrict__ x,
                const float* __restrict__ v,
                const float* __restrict__ W,
                const float* __restrict__ bias,
                float* __restrict__ result,  // [B]
                float* __restrict__ out)     // [B][ADIM]
{
    const int row = blockIdx.x * BROWS + threadIdx.x;
    const int seg = blockIdx.y;
    const int d0  = seg * SEG;

    const float* __restrict__ xp = x + (size_t)row * DDIM + d0;

    float acc[ADIM];
#pragma unroll
    for (int a = 0; a < ADIM; ++a) acc[a] = 0.f;

    for (int d = 0; d < SEG; d += 4) {
        const float4 xv = *reinterpret_cast<const float4*>(xp + d);
#pragma unroll
        for (int a = 0; a < ADIM; ++a) {
            const float4 wv =
                *reinterpret_cast<const float4*>(W + (size_t)a * DDIM + d0 + d);
            acc[a] = fmaf(xv.x, wv.x, acc[a]);
            acc[a] = fmaf(xv.y, wv.y, acc[a]);
            acc[a] = fmaf(xv.z, wv.z, acc[a]);
            acc[a] = fmaf(xv.w, wv.w, acc[a]);
        }
    }

    if (seg == 0) {
#pragma unroll
        for (int a = 0; a < ADIM; ++a) acc[a] += bias[a];
    }

    // Epilogue: accumulate out[row][a] and this segment's contribution to
    // result[row] = sum_a out[row][a] * v[row][a]  (linear in the partials).
    const float* __restrict__ vp = v + (size_t)row * ADIM;
    float* __restrict__ op = out + (size_t)row * ADIM;
    float res = 0.f;
#pragma unroll
    for (int a = 0; a < ADIM; ++a) {
        atomicAdd(op + a, acc[a]);
        res = fmaf(acc[a], vp[a], res);
    }
    atomicAdd(result + row, res);
}

extern "C" void kernel_launch(void* const* d_in, const int* in_sizes, int n_in,
                              void* d_out, int out_size, void* d_ws, size_t ws_size,
                              hipStream_t stream) {
    const float* x  = (const float*)d_in[0];
    const float* v  = (const float*)d_in[1];
    const float* W  = (const float*)d_in[2];
    const float* b  = (const float*)d_in[3];

    const int B = in_sizes[0] / DDIM;     // 16384

    float* result = (float*)d_out;        // first B floats
    float* out    = (float*)d_out + B;    // then B*ADIM floats

    // d_out is poisoned once and never re-poisoned between replays; we
    // accumulate with atomics, so zero it every launch (capture-safe).
    hipMemsetAsync(d_out, 0, (size_t)out_size * sizeof(float), stream);

    dim3 grid(B / BROWS, NSEG);
    dim3 block(BROWS);
    fem_kernel<<<grid, block, 0, stream>>>(x, v, W, b, result, out);
}

// Round 2
// 154.353 us; speedup vs baseline: 1.5458x; 1.5458x over previous
//
#include <hip/hip_runtime.h>

#define DDIM 4096
#define ADIM 21
#define NSEG 32
#define SEG  (DDIM / NSEG)   // 128
#define PAD  24              // ADIM padded to float4 multiple
#define BROWS 256

// ---------------- Stage 1: per-segment partial dot products ----------------
// Thread-per-row, D split into 32 segments -> 2048 blocks (8/CU, 32 waves/CU).
// W address is wave-uniform -> compiler emits s_load; 10.5 KB W slice is
// scalar-cache resident. x walked contiguously per thread, 4x 16B in flight.
__global__ __launch_bounds__(BROWS, 8)
void fem_partial(const float* __restrict__ x,
                 const float* __restrict__ W,
                 float* __restrict__ part,   // [NSEG][B][PAD]
                 int B)
{
    const int row = blockIdx.x * BROWS + threadIdx.x;
    const int seg = blockIdx.y;
    const int d0  = seg * SEG;

    const float* __restrict__ xp = x + (size_t)row * DDIM + d0;

    float acc[ADIM];
#pragma unroll
    for (int a = 0; a < ADIM; ++a) acc[a] = 0.f;

#pragma unroll 2
    for (int d = 0; d < SEG; d += 8) {
        const float4 xv0 = *reinterpret_cast<const float4*>(xp + d);
        const float4 xv1 = *reinterpret_cast<const float4*>(xp + d + 4);
#pragma unroll
        for (int a = 0; a < ADIM; ++a) {
            const float* wp = W + (size_t)a * DDIM + d0 + d;
            const float4 wv0 = *reinterpret_cast<const float4*>(wp);
            const float4 wv1 = *reinterpret_cast<const float4*>(wp + 4);
            acc[a] = fmaf(xv0.x, wv0.x, acc[a]);
            acc[a] = fmaf(xv0.y, wv0.y, acc[a]);
            acc[a] = fmaf(xv0.z, wv0.z, acc[a]);
            acc[a] = fmaf(xv0.w, wv0.w, acc[a]);
            acc[a] = fmaf(xv1.x, wv1.x, acc[a]);
            acc[a] = fmaf(xv1.y, wv1.y, acc[a]);
            acc[a] = fmaf(xv1.z, wv1.z, acc[a]);
            acc[a] = fmaf(xv1.w, wv1.w, acc[a]);
        }
    }

    // [seg][row][PAD]: wave writes 64 contiguous 96B chunks = 6144B contiguous
    float* pp = part + ((size_t)seg * B + row) * PAD;
#pragma unroll
    for (int k = 0; k < 5; ++k)
        *reinterpret_cast<float4*>(pp + 4 * k) =
            make_float4(acc[4 * k], acc[4 * k + 1], acc[4 * k + 2], acc[4 * k + 3]);
    pp[20] = acc[20];
}

// ---------------- Stage 2: reduce partials, apply bias, weighted sum -------
// Thread-per-row; partials are L3-resident (50 MB just written). Writes every
// element of d_out exactly once -> no memset, fully deterministic.
__global__ __launch_bounds__(BROWS, 4)
void fem_reduce(const float* __restrict__ part,  // [NSEG][B][PAD]
                const float* __restrict__ v,
                const float* __restrict__ bias,
                float* __restrict__ result,      // [B]
                float* __restrict__ out,         // [B][ADIM]
                int B)
{
    const int row = blockIdx.x * BROWS + threadIdx.x;

    float acc[ADIM];
#pragma unroll
    for (int a = 0; a < ADIM; ++a) acc[a] = bias[a];

#pragma unroll 8
    for (int s = 0; s < NSEG; ++s) {
        const float4* q =
            reinterpret_cast<const float4*>(part + ((size_t)s * B + row) * PAD);
#pragma unroll
        for (int k = 0; k < PAD / 4; ++k) {   // 6 float4 = 24 floats (3 junk)
            const float4 t = q[k];
            if (4 * k + 0 < ADIM) acc[4 * k + 0] += t.x;
            if (4 * k + 1 < ADIM) acc[4 * k + 1] += t.y;
            if (4 * k + 2 < ADIM) acc[4 * k + 2] += t.z;
            if (4 * k + 3 < ADIM) acc[4 * k + 3] += t.w;
        }
    }

    const float* __restrict__ vp = v + (size_t)row * ADIM;
    float* __restrict__ op = out + (size_t)row * ADIM;
    float res = 0.f;
#pragma unroll
    for (int a = 0; a < ADIM; ++a) {
        op[a] = acc[a];
        res = fmaf(acc[a], vp[a], res);
    }
    result[row] = res;
}

// ---------------- Fallback (ws too small): R1 atomic kernel ----------------
__global__ __launch_bounds__(BROWS, 2)
void fem_atomic(const float* __restrict__ x,
                const float* __restrict__ v,
                const float* __restrict__ W,
                const float* __restrict__ bias,
                float* __restrict__ result,
                float* __restrict__ out)
{
    const int row = blockIdx.x * BROWS + threadIdx.x;
    const int seg = blockIdx.y;
    const int d0  = seg * 512;
    const float* __restrict__ xp = x + (size_t)row * DDIM + d0;
    float acc[ADIM];
#pragma unroll
    for (int a = 0; a < ADIM; ++a) acc[a] = 0.f;
    for (int d = 0; d < 512; d += 4) {
        const float4 xv = *reinterpret_cast<const float4*>(xp + d);
#pragma unroll
        for (int a = 0; a < ADIM; ++a) {
            const float4 wv = *reinterpret_cast<const float4*>(W + (size_t)a * DDIM + d0 + d);
            acc[a] = fmaf(xv.x, wv.x, acc[a]);
            acc[a] = fmaf(xv.y, wv.y, acc[a]);
            acc[a] = fmaf(xv.z, wv.z, acc[a]);
            acc[a] = fmaf(xv.w, wv.w, acc[a]);
        }
    }
    if (seg == 0) {
#pragma unroll
        for (int a = 0; a < ADIM; ++a) acc[a] += bias[a];
    }
    const float* __restrict__ vp = v + (size_t)row * ADIM;
    float* __restrict__ op = out + (size_t)row * ADIM;
    float res = 0.f;
#pragma unroll
    for (int a = 0; a < ADIM; ++a) {
        atomicAdd(op + a, acc[a]);
        res = fmaf(acc[a], vp[a], res);
    }
    atomicAdd(result + row, res);
}

extern "C" void kernel_launch(void* const* d_in, const int* in_sizes, int n_in,
                              void* d_out, int out_size, void* d_ws, size_t ws_size,
                              hipStream_t stream) {
    const float* x  = (const float*)d_in[0];
    const float* v  = (const float*)d_in[1];
    const float* W  = (const float*)d_in[2];
    const float* b  = (const float*)d_in[3];

    const int B = in_sizes[0] / DDIM;     // 16384

    float* result = (float*)d_out;        // [B]
    float* out    = (float*)d_out + B;    // [B][ADIM]

    const size_t ws_needed = (size_t)NSEG * B * PAD * sizeof(float);

    if (ws_size >= ws_needed) {
        float* part = (float*)d_ws;
        dim3 grid1(B / BROWS, NSEG);
        fem_partial<<<grid1, dim3(BROWS), 0, stream>>>(x, W, part, B);
        fem_reduce<<<dim3(B / BROWS), dim3(BROWS), 0, stream>>>(part, v, b, result, out, B);
    } else {
        hipMemsetAsync(d_out, 0, (size_t)out_size * sizeof(float), stream);
        dim3 grid(B / BROWS, 8);
        fem_atomic<<<grid, dim3(BROWS), 0, stream>>>(x, v, W, b, result, out);
    }
}

// Round 3
// 55.212 us; speedup vs baseline: 4.3214x; 2.7956x over previous
//
#include <hip/hip_runtime.h>
#include <hip/hip_bf16.h>

#define DDIM 4096
#define ADIM 21
#define BM   64                 // rows per block
#define KC   128                // k per chunk
#define NCH  (DDIM / KC)        // 32
#define NTHR 256                // 4 waves

typedef __attribute__((ext_vector_type(8))) short bf16x8;
typedef __attribute__((ext_vector_type(4))) float f32x4;

// LDS: x tile [64][128] bf16 (16KB) x2, W tile [32][128] bf16 (8KB) x2
#define XOFF(b) ((b) * 16384)
#define WOFF(b) (32768 + (b) * 8192)

// row-major [row][k] bf16, row stride 256B; XOR-swizzle 16B granules so that
// 16 consecutive rows at the same k map to 8 distinct bank-groups (2-way=free)
__device__ __forceinline__ int swz(int row, int kbyte) {
    return (row * 256 + kbyte) ^ ((row & 7) << 4);
}

__device__ __forceinline__ unsigned pk2(float lo, float hi) {
    unsigned short a = __builtin_bit_cast(unsigned short, __float2bfloat16(lo));
    unsigned short b = __builtin_bit_cast(unsigned short, __float2bfloat16(hi));
    return (unsigned)a | ((unsigned)b << 16);
}

__global__ __launch_bounds__(NTHR, 1)
void fem_mfma(const float* __restrict__ x,
              const float* __restrict__ v,
              const float* __restrict__ W,
              const float* __restrict__ bias,
              float* __restrict__ result,   // [B]
              float* __restrict__ out)      // [B][ADIM]
{
    __shared__ char smem[49152];
    const int t = threadIdx.x;
    const int rowbase = blockIdx.x * BM;

    // ---- staging reg sets (all indices compile-time after unroll) ----
    float4 xA[8], xB[8], wA[4], wB[4];

    // granule mapping: x granule g = t + j*256 -> row g>>4, kg g&15 (8 k each)
    auto issue = [&](int c, float4 xr[8], float4 wr[4]) {
        const float* xs = x + (size_t)(rowbase + (t >> 4)) * DDIM + c * KC + (t & 15) * 8;
#pragma unroll
        for (int j = 0; j < 4; ++j) {
            const float* s = xs + (size_t)j * 16 * DDIM;
            xr[2 * j]     = *(const float4*)s;
            xr[2 * j + 1] = *(const float4*)(s + 4);
        }
        const float* ws = W + (size_t)(t >> 4) * DDIM + c * KC + (t & 15) * 8;
        wr[0] = *(const float4*)ws;
        wr[1] = *(const float4*)(ws + 4);
        if (t < 80) {                       // rows 16..20
            const float* w2 = W + (size_t)(16 + (t >> 4)) * DDIM + c * KC + (t & 15) * 8;
            wr[2] = *(const float4*)w2;
            wr[3] = *(const float4*)(w2 + 4);
        }
    };

    auto write_stage = [&](int buf, const float4 xr[8], const float4 wr[4]) {
        char* xb = smem + XOFF(buf);
        const int kg = t & 15;
#pragma unroll
        for (int j = 0; j < 4; ++j) {
            const int row = (t >> 4) + j * 16;
            uint4 g;
            g.x = pk2(xr[2 * j].x, xr[2 * j].y);
            g.y = pk2(xr[2 * j].z, xr[2 * j].w);
            g.z = pk2(xr[2 * j + 1].x, xr[2 * j + 1].y);
            g.w = pk2(xr[2 * j + 1].z, xr[2 * j + 1].w);
            *(uint4*)(xb + swz(row, kg * 16)) = g;
        }
        char* wb = smem + WOFF(buf);
        {
            uint4 g;
            g.x = pk2(wr[0].x, wr[0].y); g.y = pk2(wr[0].z, wr[0].w);
            g.z = pk2(wr[1].x, wr[1].y); g.w = pk2(wr[1].z, wr[1].w);
            *(uint4*)(wb + swz(t >> 4, kg * 16)) = g;
        }
        if (t < 80) {
            uint4 g;
            g.x = pk2(wr[2].x, wr[2].y); g.y = pk2(wr[2].z, wr[2].w);
            g.z = pk2(wr[3].x, wr[3].y); g.w = pk2(wr[3].z, wr[3].w);
            *(uint4*)(wb + swz(16 + (t >> 4), kg * 16)) = g;
        }
    };

    const int lane = t & 63;
    const int wv   = t >> 6;            // wave id 0..3, owns 16 rows
    const int a0   = lane & 15;         // annotator col for acc0
    const int kh   = (lane >> 4) * 8;   // k sub-offset within K=32
    const int rA   = wv * 16 + a0 - a0 + (lane & 15); // row within x tile

    f32x4 acc0, acc1;
    {
        const float ba0 = bias[a0];
        const float ba1 = (a0 < 5) ? bias[16 + a0] : 0.f;
        acc0 = (f32x4){ba0, ba0, ba0, ba0};
        acc1 = (f32x4){ba1, ba1, ba1, ba1};
    }

    auto compute = [&](int buf) {
        const char* xb = smem + XOFF(buf);
        const char* wb = smem + WOFF(buf);
        const int rowA = wv * 16 + (lane & 15);
#pragma unroll
        for (int k0 = 0; k0 < KC; k0 += 32) {
            bf16x8 a  = *(const bf16x8*)(xb + swz(rowA,        (k0 + kh) * 2));
            bf16x8 b0 = *(const bf16x8*)(wb + swz(a0,          (k0 + kh) * 2));
            bf16x8 b1 = *(const bf16x8*)(wb + swz(16 + a0,     (k0 + kh) * 2));
            acc0 = __builtin_amdgcn_mfma_f32_16x16x32_bf16(a, b0, acc0, 0, 0, 0);
            acc1 = __builtin_amdgcn_mfma_f32_16x16x32_bf16(a, b1, acc1, 0, 0, 0);
        }
    };

    // ---- prologue: zero-fill W rows 21..31 (both buffers), prime pipeline ----
    if (t < 176) {                       // 11 rows x 16 granules
        const int row = 21 + (t >> 4), kg = t & 15;
        const uint4 z = {0, 0, 0, 0};
        *(uint4*)(smem + WOFF(0) + swz(row, kg * 16)) = z;
        *(uint4*)(smem + WOFF(1) + swz(row, kg * 16)) = z;
    }
    issue(0, xA, wA);
    write_stage(0, xA, wA);
    issue(1, xB, wB);
    __syncthreads();

    // ---- main loop: 2 chunks per iteration, 2-deep reg-staged pipeline ----
    for (int c = 0; c < NCH; c += 2) {
        if (c + 2 < NCH) issue(c + 2, xA, wA);
        compute(0);                       // chunk c
        __syncthreads();
        write_stage(1, xB, wB);           // chunk c+1
        if (c + 3 < NCH) issue(c + 3, xB, wB);
        __syncthreads();
        compute(1);                       // chunk c+1
        __syncthreads();
        if (c + 2 < NCH) write_stage(0, xA, wA);  // chunk c+2
        __syncthreads();
    }

    // ---- epilogue: acc0 col a0 (0..15), acc1 col 16+a0 (only a0<5 real) ----
    // D layout: row = (lane>>4)*4 + reg, col = lane&15  [verified, guide §3]
    const size_t growbase = (size_t)rowbase + wv * 16 + (lane >> 4) * 4;
#pragma unroll
    for (int r = 0; r < 4; ++r) {
        const size_t row = growbase + r;
        float o0 = acc0[r];
        out[row * ADIM + a0] = o0;
        float p = o0 * v[row * ADIM + a0];
        if (a0 < 5) {
            float o1 = acc1[r];
            out[row * ADIM + 16 + a0] = o1;
            p += o1 * v[row * ADIM + 16 + a0];
        }
        p += __shfl_xor(p, 1);
        p += __shfl_xor(p, 2);
        p += __shfl_xor(p, 4);
        p += __shfl_xor(p, 8);
        if (a0 == 0) result[row] = p;
    }
}

extern "C" void kernel_launch(void* const* d_in, const int* in_sizes, int n_in,
                              void* d_out, int out_size, void* d_ws, size_t ws_size,
                              hipStream_t stream) {
    const float* x  = (const float*)d_in[0];
    const float* v  = (const float*)d_in[1];
    const float* W  = (const float*)d_in[2];
    const float* b  = (const float*)d_in[3];

    const int B = in_sizes[0] / DDIM;     // 16384

    float* result = (float*)d_out;        // [B]
    float* out    = (float*)d_out + B;    // [B][ADIM]

    fem_mfma<<<dim3(B / BM), dim3(NTHR), 0, stream>>>(x, v, W, b, result, out);
}